// Round 7
// baseline (1464.174 us; speedup 1.0000x reference)
//
#include <hip/hip_runtime.h>

// Round 13: R12 base (801us champion) + symmetric row-half work split:
//  - xpart on ALL 8 waves (w<4: rows 0-15 of tile, a0; w>=4: rows 16-31, a1);
//    halves decoder-exposed xpart(inn) after fc_wait.
//  - kreduce -> symmetric exchange (same 3 rounds/6 syncs, 4x4KB planes):
//    waves 4-7 send G0 h-partials, waves 0-3 send G1.
//  - epilogue on ALL 8 waves (8 gate-values each, own row-half) -> the
//    previously serial-exposed epilogue tail (waves 4-7 idle at arrive)
//    halves; all waves reach arrive together.
//  hpart, barrier, fcdo, LDS layouts byte-identical to R12 (R9-R11 lesson:
//  don't perturb the proven schedule). nx[4]->nxl[2], hreg[4]->hreg[2]
//  frees 16 VGPR of headroom.

typedef unsigned short ushort_t;
typedef __bf16 bf16x8 __attribute__((ext_vector_type(8)));
typedef float f32x4 __attribute__((ext_vector_type(4)));
typedef unsigned int u32x4 __attribute__((ext_vector_type(4)));

#define MFMA(a, b, c) __builtin_amdgcn_mfma_f32_16x16x32_bf16(a, b, c, 0, 0, 0)

static __device__ __forceinline__ ushort_t f2bf(float f) {
  union { float f; unsigned u; } x; x.f = f;
  unsigned r = x.u + 0x7fffu + ((x.u >> 16) & 1u);
  return (ushort_t)(r >> 16);
}
static __device__ __forceinline__ float sigmf(float x) { return 1.f / (1.f + __expf(-x)); }
static __device__ __forceinline__ float tanhf_(float x) { return 1.f - 2.f / (__expf(2.f * x) + 1.f); }

static __device__ __forceinline__ __amdgpu_buffer_rsrc_t mkrsrc(const void* p) {
  return __builtin_amdgcn_make_buffer_rsrc(const_cast<void*>(p), (short)0, -1, 0x00020000);
}
#if __has_builtin(__builtin_amdgcn_raw_buffer_load_b128)
// aux=1 -> sc0: bypass vL1 (h/inn: written by other CUs each step).
static __device__ __forceinline__ bf16x8 ldb(__amdgpu_buffer_rsrc_t r, int voff) {
  u32x4 v = __builtin_amdgcn_raw_buffer_load_b128(r, voff, 0, 1);
  union { u32x4 u; bf16x8 b; } x; x.u = v; return x.b;
}
// aux=0: vL1-cached (weights: immutable, block/group-private).
static __device__ __forceinline__ bf16x8 ldbc(__amdgpu_buffer_rsrc_t r, int voff) {
  u32x4 v = __builtin_amdgcn_raw_buffer_load_b128(r, voff, 0, 0);
  union { u32x4 u; bf16x8 b; } x; x.u = v; return x.b;
}
#else
static __device__ __forceinline__ bf16x8 ldb(__amdgpu_buffer_rsrc_t r, int voff) {
  union { unsigned u[4]; bf16x8 b; } x;
  x.u[0] = __builtin_amdgcn_raw_buffer_load_b32(r, voff, 0, 1);
  x.u[1] = __builtin_amdgcn_raw_buffer_load_b32(r, voff + 4, 0, 1);
  x.u[2] = __builtin_amdgcn_raw_buffer_load_b32(r, voff + 8, 0, 1);
  x.u[3] = __builtin_amdgcn_raw_buffer_load_b32(r, voff + 12, 0, 1);
  return x.b;
}
static __device__ __forceinline__ bf16x8 ldbc(__amdgpu_buffer_rsrc_t r, int voff) {
  union { unsigned u[4]; bf16x8 b; } x;
  x.u[0] = __builtin_amdgcn_raw_buffer_load_b32(r, voff, 0, 0);
  x.u[1] = __builtin_amdgcn_raw_buffer_load_b32(r, voff + 4, 0, 0);
  x.u[2] = __builtin_amdgcn_raw_buffer_load_b32(r, voff + 8, 0, 0);
  x.u[3] = __builtin_amdgcn_raw_buffer_load_b32(r, voff + 12, 0, 0);
  return x.b;
}
#endif

__global__ __launch_bounds__(512, 2)
void seq2seq_xcd(const float* __restrict__ enc, const float* __restrict__ dec,
                 const float* __restrict__ Wih, const float* __restrict__ Whh,
                 const float* __restrict__ b_ih, const float* __restrict__ b_hh,
                 const float* __restrict__ fcw, const float* __restrict__ fcb,
                 float* __restrict__ outp,
                 ushort_t* __restrict__ xg, ushort_t* __restrict__ hA,
                 ushort_t* __restrict__ innA, ushort_t* __restrict__ nG,
                 ushort_t* __restrict__ fcG, unsigned* cnt) {
  __shared__ ushort_t WrzL[65536];  // [kt32][gate2][jf2][512]  128 KB
  __shared__ ushort_t WiL[6144];    // [kt2][gate3][jf2][512]    12 KB
  __shared__ float scratchF[4096];  // 4 planes x 256 slots x f32x4 (conflict-free) 16 KB
  __shared__ unsigned sgs;

  const int tid = threadIdx.x;
  const int w = tid >> 6, l = tid & 63;
  const int fr = l & 15, fq4 = l >> 4;

  // ---- claim XCD-local slot ----
  if (tid == 0) {
    unsigned x;
    asm volatile("s_getreg_b32 %0, hwreg(HW_REG_XCC_ID, 0, 8)" : "=s"(x));
    x &= 7u;
    unsigned s = atomicAdd(&cnt[x * 64], 1u);
    sgs = (x << 8) | s;
  }
  __syncthreads();
  const int g = sgs >> 8, slot = sgs & 255;
  const bool isFC = (slot >= 24);

  unsigned* arrp = cnt + (8 + g) * 64;
  auto fcpp = [&](int td) { return cnt + (48 + g * 25 + td) * 64; };

  ushort_t* hbase = hA + (size_t)g * 262144;
  auto hb = [&](int i) { return hbase + (size_t)i * 131072; };
  ushort_t* xgg = xg + (size_t)g * 49 * 8192;
  auto inng = [&](int i) { return innA + (size_t)(g * 2 + i) * 8192; };
  ushort_t* nGp = nG + (size_t)(g * 32 + slot) * 32768;
  ushort_t* fcGg = fcG + (size_t)g * 65536;

  // ---- init conversions (all group-local) ----
  for (int i = tid; i < 65536; i += 512) {  // WrzL
    int j = i & 7, ln = (i >> 3) & 63, jf = (i >> 9) & 1, gt = (i >> 10) & 1, kt = i >> 11;
    int col = gt * 1024 + slot * 32 + jf * 16 + (ln & 15);
    int k = kt * 32 + (ln >> 4) * 8 + j;
    WrzL[i] = f2bf(Whh[(size_t)col * 1024 + k]);
  }
  for (int i = tid; i < 6144; i += 512) {  // WiL (r,z,n)
    int j = i & 7, ln = (i >> 3) & 63, jf = (i >> 9) & 1, rem = i >> 10;
    int gt = rem % 3, kt = rem / 3;
    int col = gt * 1024 + slot * 32 + jf * 16 + (ln & 15);
    int k = kt * 32 + (ln >> 4) * 8 + j;
    WiL[i] = (k < 55) ? f2bf(Wih[(size_t)col * 55 + k]) : (ushort_t)0;
  }
  for (int i = tid; i < 32768; i += 512) {  // nG (block-private)
    int j = i & 7, ln = (i >> 3) & 63, jf = (i >> 9) & 1, kt = i >> 10;
    int col = 2048 + slot * 32 + jf * 16 + (ln & 15);
    int k = kt * 32 + (ln >> 4) * 8 + j;
    nGp[i] = f2bf(Whh[(size_t)col * 1024 + k]);
  }
#pragma unroll
  for (int rep = 0; rep < 2; ++rep) {  // xg: t = slot, slot+32
    int t = slot + rep * 32;
    if (t < 49) {
      ushort_t* xp = xgg + (size_t)t * 8192;
      for (int i = tid; i < 8192; i += 512) {
        int sub = i & 7, row = (i >> 3) & 127, kc = i >> 10;
        int c = kc * 8 + sub;
        xp[i] = (c < 55) ? f2bf(enc[((size_t)(g * 128 + row) * 50 + t) * 55 + c]) : (ushort_t)0;
      }
    }
  }
  if (slot < 4) {  // inn(0) = dec[:,0,:]
    ushort_t* ip = inng(0);
    for (int i = slot * 2048 + tid; i < (slot + 1) * 2048; i += 512) {
      int sub = i & 7, row = (i >> 3) & 127, kc = i >> 10;
      int c = kc * 8 + sub;
      ip[i] = (c < 55) ? f2bf(dec[(size_t)(g * 128 + row) * 1375 + c]) : (ushort_t)0;
    }
  }
  if (isFC) {  // fcG: group-shared, slot s converts kt 4(s-24)..+3
    for (int i = (slot - 24) * 8192 + tid; i < (slot - 23) * 8192; i += 512) {
      int j = i & 7, ln = (i >> 3) & 63, jf = (i >> 9) & 3, kt = i >> 11;
      int c = jf * 16 + (ln & 15);
      int k = kt * 32 + (ln >> 4) * 8 + j;
      fcGg[i] = (c < 55) ? f2bf(fcw[(size_t)c * 1024 + k]) : (ushort_t)0;
    }
  }

  // ---- per-thread constants ----
  float brz[2], bzz[2], bin[2], bhn[2];
#pragma unroll
  for (int jf = 0; jf < 2; ++jf) {
    int col = slot * 32 + jf * 16 + fr;
    brz[jf] = b_ih[col] + b_hh[col];
    bzz[jf] = b_ih[1024 + col] + b_hh[1024 + col];
    bin[jf] = b_ih[2048 + col];
    bhn[jf] = b_hh[2048 + col];
  }
  const int Rfc = (slot - 24) * 16;      // FC block rows (if isFC)
  const int jfF = w & 3;
  const int colF = jfF * 16 + fr;
  float fcbF = 0.f, inp[4] = {0.f, 0.f, 0.f, 0.f};
  if (isFC && w < 4) {
    fcbF = (colF < 55) ? fcb[colF] : 0.f;
#pragma unroll
    for (int v = 0; v < 4; ++v)
      inp[v] = (colF < 55) ? dec[(size_t)(g * 128 + Rfc + fq4 * 4 + v) * 1375 + colF] : 0.f;
  }
  f32x4 hreg[2];  // per wave: its 16-row half, [jf]
#pragma unroll
  for (int i = 0; i < 2; ++i) hreg[i] = (f32x4){0.f, 0.f, 0.f, 0.f};

  // ---- flat group barrier (group = one XCD; no cache maintenance) ----
  auto arrive = [&](unsigned k) {
    (void)k;
    __syncthreads();  // drains vmcnt: all stores complete at (shared) L2
    if (tid == 0) atomicAdd(arrp, 1u);
  };
  auto wait_rel = [&](unsigned k) {  // leading sync dropped: arrive's barrier
    if (tid == 0) {                  // directly precedes with register-only work between
      while (__hip_atomic_load(arrp, __ATOMIC_RELAXED, __HIP_MEMORY_SCOPE_AGENT) < 32u * k)
        __builtin_amdgcn_s_sleep(1);
    }
    __syncthreads();
  };
  auto fc_wait = [&](int td) {
    if (tid == 0) {
      while (__hip_atomic_load(fcpp(td), __ATOMIC_RELAXED, __HIP_MEMORY_SCOPE_AGENT) < 8u)
        __builtin_amdgcn_s_sleep(1);
    }
    __syncthreads();
  };

  // ---- accumulators: r/z/nH K-split in av[12]; nX per-wave row-half ----
  f32x4 av[12], nxl[2];

  // xpart: ALL waves; w<4 handles rows R..R+15 (a0), w>=4 rows R+16..R+31 (a1)
  auto xpart = [&](const ushort_t* xp) {
    __amdgpu_buffer_rsrc_t rx = mkrsrc(xp);
    const int R = (w & 3) * 32 + (w >> 2) * 16;
#pragma unroll
    for (int kt = 0; kt < 2; ++kt) {
      bf16x8 a = ldb(rx, ((kt * 4 + fq4) * 128 + R + fr) * 16);
      const ushort_t* bl = WiL + kt * 3072 + l * 8;
#pragma unroll
      for (int jf = 0; jf < 2; ++jf) {
        bf16x8 br = *(const bf16x8*)(bl + jf * 512);
        bf16x8 bz = *(const bf16x8*)(bl + 1024 + jf * 512);
        bf16x8 bn = *(const bf16x8*)(bl + 2048 + jf * 512);
        if (w < 4) {
          av[jf] = MFMA(a, br, av[jf]);
          av[4 + jf] = MFMA(a, bz, av[4 + jf]);
        } else {
          av[2 + jf] = MFMA(a, br, av[2 + jf]);
          av[6 + jf] = MFMA(a, bz, av[6 + jf]);
        }
        nxl[jf] = MFMA(a, bn, nxl[jf]);
      }
    }
  };

  auto hpart = [&](const ushort_t* hbp) {  // all waves; K-split halves
    __amdgpu_buffer_rsrc_t r = mkrsrc(hbp);
    __amdgpu_buffer_rsrc_t rn = mkrsrc(nGp);
    const int kh = w >> 2, R = (w & 3) * 32;
    bf16x8 A0[4], A1[4];   // h fragments: depth-4 prefetch (sc0, L2)
    bf16x8 NG[4][2];       // n-gate weights: depth-4 prefetch (vL1)
#pragma unroll
    for (int i = 0; i < 4; ++i) {
      int kt = kh * 16 + i;
      A0[i] = ldb(r, ((kt * 4 + fq4) * 128 + R + fr) * 16);
      A1[i] = ldb(r, ((kt * 4 + fq4) * 128 + R + 16 + fr) * 16);
      NG[i][0] = ldbc(rn, kt * 2048 + l * 16);
      NG[i][1] = ldbc(rn, kt * 2048 + 1024 + l * 16);
    }
    // LDS B-frags: cross-iteration prefetch (depth-1)
    const ushort_t* bl0 = WrzL + (kh * 16) * 2048 + l * 8;
    bf16x8 br0 = *(const bf16x8*)(bl0);
    bf16x8 br1 = *(const bf16x8*)(bl0 + 512);
    bf16x8 bz0 = *(const bf16x8*)(bl0 + 1024);
    bf16x8 bz1 = *(const bf16x8*)(bl0 + 1536);
#pragma unroll
    for (int i = 0; i < 16; ++i) {
      int kt = kh * 16 + i;
      bf16x8 a0 = A0[i & 3], a1 = A1[i & 3];
      bf16x8 n0 = NG[i & 3][0], n1 = NG[i & 3][1];
      bf16x8 cr0 = br0, cr1 = br1, cz0 = bz0, cz1 = bz1;
      if (i < 15) {  // prefetch next iter's WrzL fragments
        const ushort_t* bln = WrzL + (kt + 1) * 2048 + l * 8;
        br0 = *(const bf16x8*)(bln);
        br1 = *(const bf16x8*)(bln + 512);
        bz0 = *(const bf16x8*)(bln + 1024);
        bz1 = *(const bf16x8*)(bln + 1536);
      }
      if (i < 12) {
        int kp = kt + 4;
        A0[i & 3] = ldb(r, ((kp * 4 + fq4) * 128 + R + fr) * 16);
        A1[i & 3] = ldb(r, ((kp * 4 + fq4) * 128 + R + 16 + fr) * 16);
        NG[i & 3][0] = ldbc(rn, kp * 2048 + l * 16);
        NG[i & 3][1] = ldbc(rn, kp * 2048 + 1024 + l * 16);
      }
      av[0] = MFMA(a0, cr0, av[0]);
      av[2] = MFMA(a1, cr0, av[2]);
      av[1] = MFMA(a0, cr1, av[1]);
      av[3] = MFMA(a1, cr1, av[3]);
      av[4] = MFMA(a0, cz0, av[4]);
      av[6] = MFMA(a1, cz0, av[6]);
      av[5] = MFMA(a0, cz1, av[5]);
      av[7] = MFMA(a1, cz1, av[7]);
      av[8] = MFMA(a0, n0, av[8]);
      av[10] = MFMA(a1, n0, av[10]);
      av[9] = MFMA(a0, n1, av[9]);
      av[11] = MFMA(a1, n1, av[11]);
    }
  };

  // Symmetric exchange: waves 4-7 send G0 (lo-rows) partials via planes 0,1;
  // waves 0-3 send G1 (hi-rows) via planes 2,3. 16B/lane -> conflict-free.
  auto kround = [&](f32x4& g0a, f32x4& g0b, f32x4& g1a, f32x4& g1b) {
    if (w >= 4) {
      float* sp = scratchF + ((w - 4) * 64 + l) * 4;
      *(f32x4*)(sp) = g0a;
      *(f32x4*)(sp + 1024) = g0b;
    } else {
      float* sp = scratchF + (w * 64 + l) * 4;
      *(f32x4*)(sp + 2048) = g1a;
      *(f32x4*)(sp + 3072) = g1b;
    }
    __syncthreads();
    if (w < 4) {
      const float* sp = scratchF + (w * 64 + l) * 4;
      g0a += *(const f32x4*)(sp);
      g0b += *(const f32x4*)(sp + 1024);
    } else {
      const float* sp = scratchF + ((w - 4) * 64 + l) * 4;
      g1a += *(const f32x4*)(sp + 2048);
      g1b += *(const f32x4*)(sp + 3072);
    }
    __syncthreads();
  };

  auto fcdo = [&](const ushort_t* hbp, int td, bool wr, ushort_t* innW) {
    __amdgpu_buffer_rsrc_t r = mkrsrc(hbp);
    __amdgpu_buffer_rsrc_t rf = mkrsrc(fcGg);
    const int kh = w >> 2;
    f32x4 fa = (f32x4){0.f, 0.f, 0.f, 0.f};
    bf16x8 Af[4], Bf[4];
#pragma unroll
    for (int i = 0; i < 4; ++i) {
      int kt = kh * 16 + i;
      Af[i] = ldb(r, ((kt * 4 + fq4) * 128 + Rfc + fr) * 16);
      Bf[i] = ldbc(rf, (kt * 4 + jfF) * 1024 + l * 16);
    }
#pragma unroll
    for (int i = 0; i < 16; ++i) {
      int kt = kh * 16 + i;
      bf16x8 a = Af[i & 3], bb = Bf[i & 3];
      if (i < 12) {
        Af[i & 3] = ldb(r, (((kt + 4) * 4 + fq4) * 128 + Rfc + fr) * 16);
        Bf[i & 3] = ldbc(rf, ((kt + 4) * 4 + jfF) * 1024 + l * 16);
      }
      fa = MFMA(a, bb, fa);
    }
    if (w >= 4) *(f32x4*)(scratchF + ((w - 4) * 64 + l) * 4) = fa;
    __syncthreads();
    if (w < 4) {
      fa += *(const f32x4*)(scratchF + (w * 64 + l) * 4);
      const int kq = colF >> 3, sub = colF & 7;
#pragma unroll
      for (int v = 0; v < 4; ++v) {
        int row = Rfc + fq4 * 4 + v;
        float o = fa[v] + inp[v] + fcbF;
        inp[v] = o;
        if (wr) innW[(kq * 128 + row) * 8 + sub] = f2bf(o);
        if (colF < 55) outp[(size_t)(g * 128 + row) * 1375 + td * 55 + colF] = o;
      }
    }
    __syncthreads();  // drains all waves' inn/out stores to L2
  };

  arrive(1);
  wait_rel(1);

  for (int t = 0; t < 74; ++t) {
#pragma unroll
    for (int i = 0; i < 12; ++i) av[i] = (f32x4){0.f, 0.f, 0.f, 0.f};
#pragma unroll
    for (int i = 0; i < 2; ++i) nxl[i] = (f32x4){0.f, 0.f, 0.f, 0.f};

    if (t <= 49) {
      xpart(t <= 48 ? xgg + (size_t)t * 8192 : inng(0));  // all waves, pre-barrier
    }
    if (t > 0) wait_rel(t + 1);
    if (t >= 50 && isFC) {
      fcdo(hb(t & 1), t - 50, true, inng((t - 49) & 1));
      if (tid == 0) atomicAdd(fcpp(t - 50), 1u);  // fcdo's barrier drained stores
    }
    if (t > 0) hpart(hb(t & 1));
    if (t >= 50) {
      fc_wait(t - 50);
      xpart(inng((t - 49) & 1));  // all waves
    }
    kround(av[0], av[1], av[2], av[3]);
    kround(av[4], av[5], av[6], av[7]);
    kround(av[8], av[9], av[10], av[11]);
    {  // epilogue on ALL waves: each wave owns its 16-row half
      ushort_t* hn = hb((t + 1) & 1);
      const int Rbase = (w & 3) * 32 + (w >> 2) * 16;
      auto epi = [&](f32x4 R_, f32x4 Z_, f32x4 NH, f32x4 NX, int jf, f32x4& hc) {
        const int kq = slot * 4 + jf * 2 + (fr >> 3), sub = fr & 7;
#pragma unroll
        for (int v = 0; v < 4; ++v) {
          float rr = sigmf(R_[v] + brz[jf]);
          float zz = sigmf(Z_[v] + bzz[jf]);
          float nn = tanhf_(NX[v] + bin[jf] + rr * (NH[v] + bhn[jf]));
          float h = (1.f - zz) * nn + zz * hc[v];
          hc[v] = h;
          int row = Rbase + fq4 * 4 + v;
          hn[(kq * 128 + row) * 8 + sub] = f2bf(h);
        }
      };
      if (w < 4) {
        epi(av[0], av[4], av[8], nxl[0], 0, hreg[0]);
        epi(av[1], av[5], av[9], nxl[1], 1, hreg[1]);
      } else {
        epi(av[2], av[6], av[10], nxl[0], 0, hreg[0]);
        epi(av[3], av[7], av[11], nxl[1], 1, hreg[1]);
      }
    }
    arrive(t + 2);
  }

  if (isFC) {
    wait_rel(75);
    fcdo(hb(0), 24, false, (ushort_t*)0);
  }
}

extern "C" void kernel_launch(void* const* d_in, const int* in_sizes, int n_in,
                              void* d_out, int out_size, void* d_ws, size_t ws_size,
                              hipStream_t stream) {
  const float* enc  = (const float*)d_in[0];
  const float* dec  = (const float*)d_in[1];
  const float* Wih  = (const float*)d_in[2];
  const float* Whh  = (const float*)d_in[3];
  const float* b_ih = (const float*)d_in[4];
  const float* b_hh = (const float*)d_in[5];
  const float* fcw  = (const float*)d_in[6];
  const float* fcb  = (const float*)d_in[7];
  float* out = (float*)d_out;

  char* ws = (char*)d_ws;
  unsigned* cnt  = (unsigned*)ws; ws += 65536;
  ushort_t* xg   = (ushort_t*)ws; ws += (size_t)8 * 49 * 8192 * 2;   // 6.42 MB
  ushort_t* hA   = (ushort_t*)ws; ws += (size_t)8 * 2 * 131072 * 2;  // 4 MB
  ushort_t* innA = (ushort_t*)ws; ws += (size_t)8 * 2 * 8192 * 2;    // 256 KB
  ushort_t* nG   = (ushort_t*)ws; ws += (size_t)8 * 32 * 32768 * 2;  // 16 MB
  ushort_t* fcG  = (ushort_t*)ws; ws += (size_t)8 * 65536 * 2;       // 1 MB

  (void)hipMemsetAsync(cnt, 0, 65536, stream);
  seq2seq_xcd<<<256, 512, 0, stream>>>(
      enc, dec, Wih, Whh, b_ih, b_hh, fcw, fcb, out,
      xg, hA, innA, nG, fcG, cnt);
}

// Round 8
// 794.009 us; speedup vs baseline: 1.8440x; 1.8440x over previous
//
#include <hip/hip_runtime.h>

// Round 14: R12 base (801us champion) + symmetric row-half split, SPILL-SAFE.
// R13 had the same design but regressed 1464us with FETCH 73->366MB and
// WRITE 186MB->1.18GB: reference-parameter lambdas (kround(f32x4&...), epi)
// made av[]/hreg addressable -> compiler demoted accumulators to scratch.
// This round: exchange + epilogue are macro-inlined, ALL av[] indices are
// compile-time literals, no address-taken registers. Design unchanged:
//  - xpart on all 8 waves (w<4: rows 0-15 of the 32-row tile; w>=4: 16-31)
//  - 3-round symmetric exchange (same 6 syncs as R12's kreduce)
//  - epilogue on all 8 waves (own row-half) -> serial tail halves
// hpart/fcdo/barriers/init byte-identical to R12.

typedef unsigned short ushort_t;
typedef __bf16 bf16x8 __attribute__((ext_vector_type(8)));
typedef float f32x4 __attribute__((ext_vector_type(4)));
typedef unsigned int u32x4 __attribute__((ext_vector_type(4)));

#define MFMA(a, b, c) __builtin_amdgcn_mfma_f32_16x16x32_bf16(a, b, c, 0, 0, 0)

static __device__ __forceinline__ ushort_t f2bf(float f) {
  union { float f; unsigned u; } x; x.f = f;
  unsigned r = x.u + 0x7fffu + ((x.u >> 16) & 1u);
  return (ushort_t)(r >> 16);
}
static __device__ __forceinline__ float sigmf(float x) { return 1.f / (1.f + __expf(-x)); }
static __device__ __forceinline__ float tanhf_(float x) { return 1.f - 2.f / (__expf(2.f * x) + 1.f); }

static __device__ __forceinline__ __amdgpu_buffer_rsrc_t mkrsrc(const void* p) {
  return __builtin_amdgcn_make_buffer_rsrc(const_cast<void*>(p), (short)0, -1, 0x00020000);
}
#if __has_builtin(__builtin_amdgcn_raw_buffer_load_b128)
// aux=1 -> sc0: bypass vL1 (h/inn: written by other CUs each step).
static __device__ __forceinline__ bf16x8 ldb(__amdgpu_buffer_rsrc_t r, int voff) {
  u32x4 v = __builtin_amdgcn_raw_buffer_load_b128(r, voff, 0, 1);
  union { u32x4 u; bf16x8 b; } x; x.u = v; return x.b;
}
// aux=0: vL1-cached (weights: immutable, block/group-private).
static __device__ __forceinline__ bf16x8 ldbc(__amdgpu_buffer_rsrc_t r, int voff) {
  u32x4 v = __builtin_amdgcn_raw_buffer_load_b128(r, voff, 0, 0);
  union { u32x4 u; bf16x8 b; } x; x.u = v; return x.b;
}
#else
static __device__ __forceinline__ bf16x8 ldb(__amdgpu_buffer_rsrc_t r, int voff) {
  union { unsigned u[4]; bf16x8 b; } x;
  x.u[0] = __builtin_amdgcn_raw_buffer_load_b32(r, voff, 0, 1);
  x.u[1] = __builtin_amdgcn_raw_buffer_load_b32(r, voff + 4, 0, 1);
  x.u[2] = __builtin_amdgcn_raw_buffer_load_b32(r, voff + 8, 0, 1);
  x.u[3] = __builtin_amdgcn_raw_buffer_load_b32(r, voff + 12, 0, 1);
  return x.b;
}
static __device__ __forceinline__ bf16x8 ldbc(__amdgpu_buffer_rsrc_t r, int voff) {
  union { unsigned u[4]; bf16x8 b; } x;
  x.u[0] = __builtin_amdgcn_raw_buffer_load_b32(r, voff, 0, 0);
  x.u[1] = __builtin_amdgcn_raw_buffer_load_b32(r, voff + 4, 0, 0);
  x.u[2] = __builtin_amdgcn_raw_buffer_load_b32(r, voff + 8, 0, 0);
  x.u[3] = __builtin_amdgcn_raw_buffer_load_b32(r, voff + 12, 0, 0);
  return x.b;
}
#endif

__global__ __launch_bounds__(512, 2)
void seq2seq_xcd(const float* __restrict__ enc, const float* __restrict__ dec,
                 const float* __restrict__ Wih, const float* __restrict__ Whh,
                 const float* __restrict__ b_ih, const float* __restrict__ b_hh,
                 const float* __restrict__ fcw, const float* __restrict__ fcb,
                 float* __restrict__ outp,
                 ushort_t* __restrict__ xg, ushort_t* __restrict__ hA,
                 ushort_t* __restrict__ innA, ushort_t* __restrict__ nG,
                 ushort_t* __restrict__ fcG, unsigned* cnt) {
  __shared__ ushort_t WrzL[65536];  // [kt32][gate2][jf2][512]  128 KB
  __shared__ ushort_t WiL[6144];    // [kt2][gate3][jf2][512]    12 KB
  __shared__ float scratchF[4096];  // 4 planes x 256 slots x f32x4 (conflict-free) 16 KB
  __shared__ unsigned sgs;

  const int tid = threadIdx.x;
  const int w = tid >> 6, l = tid & 63;
  const int fr = l & 15, fq4 = l >> 4;

  // ---- claim XCD-local slot ----
  if (tid == 0) {
    unsigned x;
    asm volatile("s_getreg_b32 %0, hwreg(HW_REG_XCC_ID, 0, 8)" : "=s"(x));
    x &= 7u;
    unsigned s = atomicAdd(&cnt[x * 64], 1u);
    sgs = (x << 8) | s;
  }
  __syncthreads();
  const int g = sgs >> 8, slot = sgs & 255;
  const bool isFC = (slot >= 24);

  unsigned* arrp = cnt + (8 + g) * 64;
  auto fcpp = [&](int td) { return cnt + (48 + g * 25 + td) * 64; };

  ushort_t* hbase = hA + (size_t)g * 262144;
  auto hb = [&](int i) { return hbase + (size_t)i * 131072; };
  ushort_t* xgg = xg + (size_t)g * 49 * 8192;
  auto inng = [&](int i) { return innA + (size_t)(g * 2 + i) * 8192; };
  ushort_t* nGp = nG + (size_t)(g * 32 + slot) * 32768;
  ushort_t* fcGg = fcG + (size_t)g * 65536;

  // ---- init conversions (all group-local) ----
  for (int i = tid; i < 65536; i += 512) {  // WrzL
    int j = i & 7, ln = (i >> 3) & 63, jf = (i >> 9) & 1, gt = (i >> 10) & 1, kt = i >> 11;
    int col = gt * 1024 + slot * 32 + jf * 16 + (ln & 15);
    int k = kt * 32 + (ln >> 4) * 8 + j;
    WrzL[i] = f2bf(Whh[(size_t)col * 1024 + k]);
  }
  for (int i = tid; i < 6144; i += 512) {  // WiL (r,z,n)
    int j = i & 7, ln = (i >> 3) & 63, jf = (i >> 9) & 1, rem = i >> 10;
    int gt = rem % 3, kt = rem / 3;
    int col = gt * 1024 + slot * 32 + jf * 16 + (ln & 15);
    int k = kt * 32 + (ln >> 4) * 8 + j;
    WiL[i] = (k < 55) ? f2bf(Wih[(size_t)col * 55 + k]) : (ushort_t)0;
  }
  for (int i = tid; i < 32768; i += 512) {  // nG (block-private)
    int j = i & 7, ln = (i >> 3) & 63, jf = (i >> 9) & 1, kt = i >> 10;
    int col = 2048 + slot * 32 + jf * 16 + (ln & 15);
    int k = kt * 32 + (ln >> 4) * 8 + j;
    nGp[i] = f2bf(Whh[(size_t)col * 1024 + k]);
  }
#pragma unroll
  for (int rep = 0; rep < 2; ++rep) {  // xg: t = slot, slot+32
    int t = slot + rep * 32;
    if (t < 49) {
      ushort_t* xp = xgg + (size_t)t * 8192;
      for (int i = tid; i < 8192; i += 512) {
        int sub = i & 7, row = (i >> 3) & 127, kc = i >> 10;
        int c = kc * 8 + sub;
        xp[i] = (c < 55) ? f2bf(enc[((size_t)(g * 128 + row) * 50 + t) * 55 + c]) : (ushort_t)0;
      }
    }
  }
  if (slot < 4) {  // inn(0) = dec[:,0,:]
    ushort_t* ip = inng(0);
    for (int i = slot * 2048 + tid; i < (slot + 1) * 2048; i += 512) {
      int sub = i & 7, row = (i >> 3) & 127, kc = i >> 10;
      int c = kc * 8 + sub;
      ip[i] = (c < 55) ? f2bf(dec[(size_t)(g * 128 + row) * 1375 + c]) : (ushort_t)0;
    }
  }
  if (isFC) {  // fcG: group-shared, slot s converts kt 4(s-24)..+3
    for (int i = (slot - 24) * 8192 + tid; i < (slot - 23) * 8192; i += 512) {
      int j = i & 7, ln = (i >> 3) & 63, jf = (i >> 9) & 3, kt = i >> 11;
      int c = jf * 16 + (ln & 15);
      int k = kt * 32 + (ln >> 4) * 8 + j;
      fcGg[i] = (c < 55) ? f2bf(fcw[(size_t)c * 1024 + k]) : (ushort_t)0;
    }
  }

  // ---- per-thread constants ----
  float brz[2], bzz[2], bin[2], bhn[2];
#pragma unroll
  for (int jf = 0; jf < 2; ++jf) {
    int col = slot * 32 + jf * 16 + fr;
    brz[jf] = b_ih[col] + b_hh[col];
    bzz[jf] = b_ih[1024 + col] + b_hh[1024 + col];
    bin[jf] = b_ih[2048 + col];
    bhn[jf] = b_hh[2048 + col];
  }
  const int Rfc = (slot - 24) * 16;      // FC block rows (if isFC)
  const int jfF = w & 3;
  const int colF = jfF * 16 + fr;
  float fcbF = 0.f, inp[4] = {0.f, 0.f, 0.f, 0.f};
  if (isFC && w < 4) {
    fcbF = (colF < 55) ? fcb[colF] : 0.f;
#pragma unroll
    for (int v = 0; v < 4; ++v)
      inp[v] = (colF < 55) ? dec[(size_t)(g * 128 + Rfc + fq4 * 4 + v) * 1375 + colF] : 0.f;
  }
  f32x4 hreg0 = (f32x4){0.f, 0.f, 0.f, 0.f};  // own row-half, jf=0
  f32x4 hreg1 = (f32x4){0.f, 0.f, 0.f, 0.f};  // own row-half, jf=1

  // ---- flat group barrier (group = one XCD; no cache maintenance) ----
  auto arrive = [&](unsigned k) {
    (void)k;
    __syncthreads();  // drains vmcnt: all stores complete at (shared) L2
    if (tid == 0) atomicAdd(arrp, 1u);
  };
  auto wait_rel = [&](unsigned k) {  // leading sync dropped: arrive's barrier
    if (tid == 0) {                  // directly precedes with register-only work between
      while (__hip_atomic_load(arrp, __ATOMIC_RELAXED, __HIP_MEMORY_SCOPE_AGENT) < 32u * k)
        __builtin_amdgcn_s_sleep(1);
    }
    __syncthreads();
  };
  auto fc_wait = [&](int td) {
    if (tid == 0) {
      while (__hip_atomic_load(fcpp(td), __ATOMIC_RELAXED, __HIP_MEMORY_SCOPE_AGENT) < 8u)
        __builtin_amdgcn_s_sleep(1);
    }
    __syncthreads();
  };

  // ---- accumulators: r/z/nH K-split in av[12]; nX per-wave row-half ----
  f32x4 av[12], nx0, nx1;

  // xpart: ALL waves; w<4 handles rows R..R+15 (a0 slots), w>=4 rows R+16..R+31
  auto xpart = [&](const ushort_t* xp) {
    __amdgpu_buffer_rsrc_t rx = mkrsrc(xp);
    const int R = (w & 3) * 32 + (w >> 2) * 16;
#pragma unroll
    for (int kt = 0; kt < 2; ++kt) {
      bf16x8 a = ldb(rx, ((kt * 4 + fq4) * 128 + R + fr) * 16);
      const ushort_t* bl = WiL + kt * 3072 + l * 8;
      bf16x8 br_0 = *(const bf16x8*)(bl);
      bf16x8 br_1 = *(const bf16x8*)(bl + 512);
      bf16x8 bz_0 = *(const bf16x8*)(bl + 1024);
      bf16x8 bz_1 = *(const bf16x8*)(bl + 1536);
      bf16x8 bn_0 = *(const bf16x8*)(bl + 2048);
      bf16x8 bn_1 = *(const bf16x8*)(bl + 2560);
      if (w < 4) {
        av[0] = MFMA(a, br_0, av[0]);
        av[1] = MFMA(a, br_1, av[1]);
        av[4] = MFMA(a, bz_0, av[4]);
        av[5] = MFMA(a, bz_1, av[5]);
      } else {
        av[2] = MFMA(a, br_0, av[2]);
        av[3] = MFMA(a, br_1, av[3]);
        av[6] = MFMA(a, bz_0, av[6]);
        av[7] = MFMA(a, bz_1, av[7]);
      }
      nx0 = MFMA(a, bn_0, nx0);
      nx1 = MFMA(a, bn_1, nx1);
    }
  };

  auto hpart = [&](const ushort_t* hbp) {  // all waves; K-split halves
    __amdgpu_buffer_rsrc_t r = mkrsrc(hbp);
    __amdgpu_buffer_rsrc_t rn = mkrsrc(nGp);
    const int kh = w >> 2, R = (w & 3) * 32;
    bf16x8 A0[4], A1[4];   // h fragments: depth-4 prefetch (sc0, L2)
    bf16x8 NG[4][2];       // n-gate weights: depth-4 prefetch (vL1)
#pragma unroll
    for (int i = 0; i < 4; ++i) {
      int kt = kh * 16 + i;
      A0[i] = ldb(r, ((kt * 4 + fq4) * 128 + R + fr) * 16);
      A1[i] = ldb(r, ((kt * 4 + fq4) * 128 + R + 16 + fr) * 16);
      NG[i][0] = ldbc(rn, kt * 2048 + l * 16);
      NG[i][1] = ldbc(rn, kt * 2048 + 1024 + l * 16);
    }
    // LDS B-frags: cross-iteration prefetch (depth-1)
    const ushort_t* bl0 = WrzL + (kh * 16) * 2048 + l * 8;
    bf16x8 br0 = *(const bf16x8*)(bl0);
    bf16x8 br1 = *(const bf16x8*)(bl0 + 512);
    bf16x8 bz0 = *(const bf16x8*)(bl0 + 1024);
    bf16x8 bz1 = *(const bf16x8*)(bl0 + 1536);
#pragma unroll
    for (int i = 0; i < 16; ++i) {
      int kt = kh * 16 + i;
      bf16x8 a0 = A0[i & 3], a1 = A1[i & 3];
      bf16x8 n0 = NG[i & 3][0], n1 = NG[i & 3][1];
      bf16x8 cr0 = br0, cr1 = br1, cz0 = bz0, cz1 = bz1;
      if (i < 15) {  // prefetch next iter's WrzL fragments
        const ushort_t* bln = WrzL + (kt + 1) * 2048 + l * 8;
        br0 = *(const bf16x8*)(bln);
        br1 = *(const bf16x8*)(bln + 512);
        bz0 = *(const bf16x8*)(bln + 1024);
        bz1 = *(const bf16x8*)(bln + 1536);
      }
      if (i < 12) {
        int kp = kt + 4;
        A0[i & 3] = ldb(r, ((kp * 4 + fq4) * 128 + R + fr) * 16);
        A1[i & 3] = ldb(r, ((kp * 4 + fq4) * 128 + R + 16 + fr) * 16);
        NG[i & 3][0] = ldbc(rn, kp * 2048 + l * 16);
        NG[i & 3][1] = ldbc(rn, kp * 2048 + 1024 + l * 16);
      }
      av[0] = MFMA(a0, cr0, av[0]);
      av[2] = MFMA(a1, cr0, av[2]);
      av[1] = MFMA(a0, cr1, av[1]);
      av[3] = MFMA(a1, cr1, av[3]);
      av[4] = MFMA(a0, cz0, av[4]);
      av[6] = MFMA(a1, cz0, av[6]);
      av[5] = MFMA(a0, cz1, av[5]);
      av[7] = MFMA(a1, cz1, av[7]);
      av[8] = MFMA(a0, n0, av[8]);
      av[10] = MFMA(a1, n0, av[10]);
      av[9] = MFMA(a0, n1, av[9]);
      av[11] = MFMA(a1, n1, av[11]);
    }
  };

// Symmetric exchange round: w>=4 sends lo-row partials av[LO0],av[LO1]
// (planes 0,1); w<4 sends hi-row partials av[HI0],av[HI1] (planes 2,3).
// All indices compile-time literals; 16B/lane contiguous -> conflict-free.
#define KXCH(LO0, LO1, HI0, HI1)                                    \
  do {                                                              \
    if (w >= 4) {                                                   \
      float* sp_ = scratchF + ((w - 4) * 64 + l) * 4;               \
      *(f32x4*)(sp_) = av[LO0];                                     \
      *(f32x4*)(sp_ + 1024) = av[LO1];                              \
    } else {                                                        \
      float* sp_ = scratchF + (w * 64 + l) * 4;                     \
      *(f32x4*)(sp_ + 2048) = av[HI0];                              \
      *(f32x4*)(sp_ + 3072) = av[HI1];                              \
    }                                                               \
    __syncthreads();                                                \
    if (w < 4) {                                                    \
      const float* sp_ = scratchF + (w * 64 + l) * 4;               \
      av[LO0] += *(const f32x4*)(sp_);                              \
      av[LO1] += *(const f32x4*)(sp_ + 1024);                       \
    } else {                                                        \
      const float* sp_ = scratchF + ((w - 4) * 64 + l) * 4;         \
      av[HI0] += *(const f32x4*)(sp_ + 2048);                       \
      av[HI1] += *(const f32x4*)(sp_ + 3072);                       \
    }                                                               \
    __syncthreads();                                                \
  } while (0)

// Epilogue gate-math for one jf; all operands literal-indexed registers.
#define EPI(RV, ZV, NHV, NXV, JF, HC)                                  \
  do {                                                                 \
    const int kq_ = slot * 4 + (JF)*2 + (fr >> 3);                     \
    _Pragma("unroll") for (int v = 0; v < 4; ++v) {                    \
      float rr = sigmf(RV[v] + brz[JF]);                               \
      float zz = sigmf(ZV[v] + bzz[JF]);                               \
      float nn = tanhf_(NXV[v] + bin[JF] + rr * (NHV[v] + bhn[JF]));   \
      float h = (1.f - zz) * nn + zz * HC[v];                          \
      HC[v] = h;                                                       \
      int row_ = Rbase + fq4 * 4 + v;                                  \
      hn[(kq_ * 128 + row_) * 8 + sub_] = f2bf(h);                     \
    }                                                                  \
  } while (0)

  auto fcdo = [&](const ushort_t* hbp, int td, bool wr, ushort_t* innW) {
    __amdgpu_buffer_rsrc_t r = mkrsrc(hbp);
    __amdgpu_buffer_rsrc_t rf = mkrsrc(fcGg);
    const int kh = w >> 2;
    f32x4 fa = (f32x4){0.f, 0.f, 0.f, 0.f};
    bf16x8 Af[4], Bf[4];
#pragma unroll
    for (int i = 0; i < 4; ++i) {
      int kt = kh * 16 + i;
      Af[i] = ldb(r, ((kt * 4 + fq4) * 128 + Rfc + fr) * 16);
      Bf[i] = ldbc(rf, (kt * 4 + jfF) * 1024 + l * 16);
    }
#pragma unroll
    for (int i = 0; i < 16; ++i) {
      int kt = kh * 16 + i;
      bf16x8 a = Af[i & 3], bb = Bf[i & 3];
      if (i < 12) {
        Af[i & 3] = ldb(r, (((kt + 4) * 4 + fq4) * 128 + Rfc + fr) * 16);
        Bf[i & 3] = ldbc(rf, ((kt + 4) * 4 + jfF) * 1024 + l * 16);
      }
      fa = MFMA(a, bb, fa);
    }
    if (w >= 4) *(f32x4*)(scratchF + ((w - 4) * 64 + l) * 4) = fa;
    __syncthreads();
    if (w < 4) {
      fa += *(const f32x4*)(scratchF + (w * 64 + l) * 4);
      const int kq = colF >> 3, sub = colF & 7;
#pragma unroll
      for (int v = 0; v < 4; ++v) {
        int row = Rfc + fq4 * 4 + v;
        float o = fa[v] + inp[v] + fcbF;
        inp[v] = o;
        if (wr) innW[(kq * 128 + row) * 8 + sub] = f2bf(o);
        if (colF < 55) outp[(size_t)(g * 128 + row) * 1375 + td * 55 + colF] = o;
      }
    }
    __syncthreads();  // drains all waves' inn/out stores to L2
  };

  arrive(1);
  wait_rel(1);

  for (int t = 0; t < 74; ++t) {
#pragma unroll
    for (int i = 0; i < 12; ++i) av[i] = (f32x4){0.f, 0.f, 0.f, 0.f};
    nx0 = (f32x4){0.f, 0.f, 0.f, 0.f};
    nx1 = (f32x4){0.f, 0.f, 0.f, 0.f};

    if (t <= 49) {
      xpart(t <= 48 ? xgg + (size_t)t * 8192 : inng(0));  // all waves, pre-barrier
    }
    if (t > 0) wait_rel(t + 1);
    if (t >= 50 && isFC) {
      fcdo(hb(t & 1), t - 50, true, inng((t - 49) & 1));
      if (tid == 0) atomicAdd(fcpp(t - 50), 1u);  // fcdo's barrier drained stores
    }
    if (t > 0) hpart(hb(t & 1));
    if (t >= 50) {
      fc_wait(t - 50);
      xpart(inng((t - 49) & 1));  // all waves
    }
    KXCH(0, 1, 2, 3);
    KXCH(4, 5, 6, 7);
    KXCH(8, 9, 10, 11);
    {  // epilogue on ALL waves: each wave owns its 16-row half
      ushort_t* hn = hb((t + 1) & 1);
      const int Rbase = (w & 3) * 32 + (w >> 2) * 16;
      const int sub_ = fr & 7;
      if (w < 4) {
        EPI(av[0], av[4], av[8], nx0, 0, hreg0);
        EPI(av[1], av[5], av[9], nx1, 1, hreg1);
      } else {
        EPI(av[2], av[6], av[10], nx0, 0, hreg0);
        EPI(av[3], av[7], av[11], nx1, 1, hreg1);
      }
    }
    arrive(t + 2);
  }

  if (isFC) {
    wait_rel(75);
    fcdo(hb(0), 24, false, (ushort_t*)0);
  }
}

extern "C" void kernel_launch(void* const* d_in, const int* in_sizes, int n_in,
                              void* d_out, int out_size, void* d_ws, size_t ws_size,
                              hipStream_t stream) {
  const float* enc  = (const float*)d_in[0];
  const float* dec  = (const float*)d_in[1];
  const float* Wih  = (const float*)d_in[2];
  const float* Whh  = (const float*)d_in[3];
  const float* b_ih = (const float*)d_in[4];
  const float* b_hh = (const float*)d_in[5];
  const float* fcw  = (const float*)d_in[6];
  const float* fcb  = (const float*)d_in[7];
  float* out = (float*)d_out;

  char* ws = (char*)d_ws;
  unsigned* cnt  = (unsigned*)ws; ws += 65536;
  ushort_t* xg   = (ushort_t*)ws; ws += (size_t)8 * 49 * 8192 * 2;   // 6.42 MB
  ushort_t* hA   = (ushort_t*)ws; ws += (size_t)8 * 2 * 131072 * 2;  // 4 MB
  ushort_t* innA = (ushort_t*)ws; ws += (size_t)8 * 2 * 8192 * 2;    // 256 KB
  ushort_t* nG   = (ushort_t*)ws; ws += (size_t)8 * 32 * 32768 * 2;  // 16 MB
  ushort_t* fcG  = (ushort_t*)ws; ws += (size_t)8 * 65536 * 2;       // 1 MB

  (void)hipMemsetAsync(cnt, 0, 65536, stream);
  seq2seq_xcd<<<256, 512, 0, stream>>>(
      enc, dec, Wih, Whh, b_ih, b_hh, fcw, fcb, out,
      xg, hA, innA, nG, fcG, cnt);
}

// Round 9
// 781.580 us; speedup vs baseline: 1.8734x; 1.0159x over previous
//
#include <hip/hip_runtime.h>

// Round 15: R14 base (794us champion) + three serial-sliver cuts:
//  (i) KXCH round-3 trailing __syncthreads dropped (provably redundant:
//      next scratch write is ordered by arrive's barrier). -1 sync/step.
//  (ii) hpart split hpre/hmain: NG initial prefetch (8 ldbc) + WrzL primer
//      (4 ds_read_b128) hoisted BEFORE wait_rel -- none depend on h(t), so
//      they complete during the barrier wait; only A-load latency remains
//      exposed post-barrier. Persistent pN0/pN1/pb* regs (+~48 VGPR live
//      range; spill falsifier = FETCH/WRITE balloon per R9).
//  (iii) arrive counter split across 4 L2 lines (slot&3): 32 same-line
//      atomicAdds/step -> 8/line; wait_rel sums 4 monotonic loads (sum <=
//      true count -> never releases early).
// Everything else byte-identical to R14.

typedef unsigned short ushort_t;
typedef __bf16 bf16x8 __attribute__((ext_vector_type(8)));
typedef float f32x4 __attribute__((ext_vector_type(4)));
typedef unsigned int u32x4 __attribute__((ext_vector_type(4)));

#define MFMA(a, b, c) __builtin_amdgcn_mfma_f32_16x16x32_bf16(a, b, c, 0, 0, 0)

static __device__ __forceinline__ ushort_t f2bf(float f) {
  union { float f; unsigned u; } x; x.f = f;
  unsigned r = x.u + 0x7fffu + ((x.u >> 16) & 1u);
  return (ushort_t)(r >> 16);
}
static __device__ __forceinline__ float sigmf(float x) { return 1.f / (1.f + __expf(-x)); }
static __device__ __forceinline__ float tanhf_(float x) { return 1.f - 2.f / (__expf(2.f * x) + 1.f); }

static __device__ __forceinline__ __amdgpu_buffer_rsrc_t mkrsrc(const void* p) {
  return __builtin_amdgcn_make_buffer_rsrc(const_cast<void*>(p), (short)0, -1, 0x00020000);
}
#if __has_builtin(__builtin_amdgcn_raw_buffer_load_b128)
// aux=1 -> sc0: bypass vL1 (h/inn: written by other CUs each step).
static __device__ __forceinline__ bf16x8 ldb(__amdgpu_buffer_rsrc_t r, int voff) {
  u32x4 v = __builtin_amdgcn_raw_buffer_load_b128(r, voff, 0, 1);
  union { u32x4 u; bf16x8 b; } x; x.u = v; return x.b;
}
// aux=0: vL1-cached (weights: immutable, block/group-private).
static __device__ __forceinline__ bf16x8 ldbc(__amdgpu_buffer_rsrc_t r, int voff) {
  u32x4 v = __builtin_amdgcn_raw_buffer_load_b128(r, voff, 0, 0);
  union { u32x4 u; bf16x8 b; } x; x.u = v; return x.b;
}
#else
static __device__ __forceinline__ bf16x8 ldb(__amdgpu_buffer_rsrc_t r, int voff) {
  union { unsigned u[4]; bf16x8 b; } x;
  x.u[0] = __builtin_amdgcn_raw_buffer_load_b32(r, voff, 0, 1);
  x.u[1] = __builtin_amdgcn_raw_buffer_load_b32(r, voff + 4, 0, 1);
  x.u[2] = __builtin_amdgcn_raw_buffer_load_b32(r, voff + 8, 0, 1);
  x.u[3] = __builtin_amdgcn_raw_buffer_load_b32(r, voff + 12, 0, 1);
  return x.b;
}
static __device__ __forceinline__ bf16x8 ldbc(__amdgpu_buffer_rsrc_t r, int voff) {
  union { unsigned u[4]; bf16x8 b; } x;
  x.u[0] = __builtin_amdgcn_raw_buffer_load_b32(r, voff, 0, 0);
  x.u[1] = __builtin_amdgcn_raw_buffer_load_b32(r, voff + 4, 0, 0);
  x.u[2] = __builtin_amdgcn_raw_buffer_load_b32(r, voff + 8, 0, 0);
  x.u[3] = __builtin_amdgcn_raw_buffer_load_b32(r, voff + 12, 0, 0);
  return x.b;
}
#endif

__global__ __launch_bounds__(512, 2)
void seq2seq_xcd(const float* __restrict__ enc, const float* __restrict__ dec,
                 const float* __restrict__ Wih, const float* __restrict__ Whh,
                 const float* __restrict__ b_ih, const float* __restrict__ b_hh,
                 const float* __restrict__ fcw, const float* __restrict__ fcb,
                 float* __restrict__ outp,
                 ushort_t* __restrict__ xg, ushort_t* __restrict__ hA,
                 ushort_t* __restrict__ innA, ushort_t* __restrict__ nG,
                 ushort_t* __restrict__ fcG, unsigned* cnt) {
  __shared__ ushort_t WrzL[65536];  // [kt32][gate2][jf2][512]  128 KB
  __shared__ ushort_t WiL[6144];    // [kt2][gate3][jf2][512]    12 KB
  __shared__ float scratchF[4096];  // 4 planes x 256 slots x f32x4 (conflict-free) 16 KB
  __shared__ unsigned sgs;

  const int tid = threadIdx.x;
  const int w = tid >> 6, l = tid & 63;
  const int fr = l & 15, fq4 = l >> 4;

  // ---- claim XCD-local slot ----
  if (tid == 0) {
    unsigned x;
    asm volatile("s_getreg_b32 %0, hwreg(HW_REG_XCC_ID, 0, 8)" : "=s"(x));
    x &= 7u;
    unsigned s = atomicAdd(&cnt[x * 64], 1u);
    sgs = (x << 8) | s;
  }
  __syncthreads();
  const int g = sgs >> 8, slot = sgs & 255;
  const bool isFC = (slot >= 24);

  // arrive counters: 4 lines per group (lines 8..39); fcpp at 48+.
  unsigned* arr4 = cnt + (8 + g * 4 + (slot & 3)) * 64;
  unsigned* arrb = cnt + (8 + g * 4) * 64;
  auto fcpp = [&](int td) { return cnt + (48 + g * 25 + td) * 64; };

  ushort_t* hbase = hA + (size_t)g * 262144;
  auto hb = [&](int i) { return hbase + (size_t)i * 131072; };
  ushort_t* xgg = xg + (size_t)g * 49 * 8192;
  auto inng = [&](int i) { return innA + (size_t)(g * 2 + i) * 8192; };
  ushort_t* nGp = nG + (size_t)(g * 32 + slot) * 32768;
  ushort_t* fcGg = fcG + (size_t)g * 65536;

  // ---- init conversions (all group-local) ----
  for (int i = tid; i < 65536; i += 512) {  // WrzL
    int j = i & 7, ln = (i >> 3) & 63, jf = (i >> 9) & 1, gt = (i >> 10) & 1, kt = i >> 11;
    int col = gt * 1024 + slot * 32 + jf * 16 + (ln & 15);
    int k = kt * 32 + (ln >> 4) * 8 + j;
    WrzL[i] = f2bf(Whh[(size_t)col * 1024 + k]);
  }
  for (int i = tid; i < 6144; i += 512) {  // WiL (r,z,n)
    int j = i & 7, ln = (i >> 3) & 63, jf = (i >> 9) & 1, rem = i >> 10;
    int gt = rem % 3, kt = rem / 3;
    int col = gt * 1024 + slot * 32 + jf * 16 + (ln & 15);
    int k = kt * 32 + (ln >> 4) * 8 + j;
    WiL[i] = (k < 55) ? f2bf(Wih[(size_t)col * 55 + k]) : (ushort_t)0;
  }
  for (int i = tid; i < 32768; i += 512) {  // nG (block-private)
    int j = i & 7, ln = (i >> 3) & 63, jf = (i >> 9) & 1, kt = i >> 10;
    int col = 2048 + slot * 32 + jf * 16 + (ln & 15);
    int k = kt * 32 + (ln >> 4) * 8 + j;
    nGp[i] = f2bf(Whh[(size_t)col * 1024 + k]);
  }
#pragma unroll
  for (int rep = 0; rep < 2; ++rep) {  // xg: t = slot, slot+32
    int t = slot + rep * 32;
    if (t < 49) {
      ushort_t* xp = xgg + (size_t)t * 8192;
      for (int i = tid; i < 8192; i += 512) {
        int sub = i & 7, row = (i >> 3) & 127, kc = i >> 10;
        int c = kc * 8 + sub;
        xp[i] = (c < 55) ? f2bf(enc[((size_t)(g * 128 + row) * 50 + t) * 55 + c]) : (ushort_t)0;
      }
    }
  }
  if (slot < 4) {  // inn(0) = dec[:,0,:]
    ushort_t* ip = inng(0);
    for (int i = slot * 2048 + tid; i < (slot + 1) * 2048; i += 512) {
      int sub = i & 7, row = (i >> 3) & 127, kc = i >> 10;
      int c = kc * 8 + sub;
      ip[i] = (c < 55) ? f2bf(dec[(size_t)(g * 128 + row) * 1375 + c]) : (ushort_t)0;
    }
  }
  if (isFC) {  // fcG: group-shared, slot s converts kt 4(s-24)..+3
    for (int i = (slot - 24) * 8192 + tid; i < (slot - 23) * 8192; i += 512) {
      int j = i & 7, ln = (i >> 3) & 63, jf = (i >> 9) & 3, kt = i >> 11;
      int c = jf * 16 + (ln & 15);
      int k = kt * 32 + (ln >> 4) * 8 + j;
      fcGg[i] = (c < 55) ? f2bf(fcw[(size_t)c * 1024 + k]) : (ushort_t)0;
    }
  }

  // ---- per-thread constants ----
  float brz[2], bzz[2], bin[2], bhn[2];
#pragma unroll
  for (int jf = 0; jf < 2; ++jf) {
    int col = slot * 32 + jf * 16 + fr;
    brz[jf] = b_ih[col] + b_hh[col];
    bzz[jf] = b_ih[1024 + col] + b_hh[1024 + col];
    bin[jf] = b_ih[2048 + col];
    bhn[jf] = b_hh[2048 + col];
  }
  const int Rfc = (slot - 24) * 16;      // FC block rows (if isFC)
  const int jfF = w & 3;
  const int colF = jfF * 16 + fr;
  float fcbF = 0.f, inp[4] = {0.f, 0.f, 0.f, 0.f};
  if (isFC && w < 4) {
    fcbF = (colF < 55) ? fcb[colF] : 0.f;
#pragma unroll
    for (int v = 0; v < 4; ++v)
      inp[v] = (colF < 55) ? dec[(size_t)(g * 128 + Rfc + fq4 * 4 + v) * 1375 + colF] : 0.f;
  }
  f32x4 hreg0 = (f32x4){0.f, 0.f, 0.f, 0.f};  // own row-half, jf=0
  f32x4 hreg1 = (f32x4){0.f, 0.f, 0.f, 0.f};  // own row-half, jf=1

  // ---- flat group barrier: 4-line arrive, sum-poll release ----
  auto arrive = [&]() {
    __syncthreads();  // drains vmcnt: all stores complete at (shared) L2
    if (tid == 0) atomicAdd(arr4, 1u);
  };
  auto wait_rel = [&](unsigned k) {
    if (tid == 0) {
      for (;;) {
        unsigned s0 = __hip_atomic_load(arrb, __ATOMIC_RELAXED, __HIP_MEMORY_SCOPE_AGENT);
        unsigned s1 = __hip_atomic_load(arrb + 64, __ATOMIC_RELAXED, __HIP_MEMORY_SCOPE_AGENT);
        unsigned s2 = __hip_atomic_load(arrb + 128, __ATOMIC_RELAXED, __HIP_MEMORY_SCOPE_AGENT);
        unsigned s3 = __hip_atomic_load(arrb + 192, __ATOMIC_RELAXED, __HIP_MEMORY_SCOPE_AGENT);
        if (s0 + s1 + s2 + s3 >= 32u * k) break;
        __builtin_amdgcn_s_sleep(1);
      }
    }
    __syncthreads();
  };
  auto fc_wait = [&](int td) {
    if (tid == 0) {
      while (__hip_atomic_load(fcpp(td), __ATOMIC_RELAXED, __HIP_MEMORY_SCOPE_AGENT) < 8u)
        __builtin_amdgcn_s_sleep(1);
    }
    __syncthreads();
  };

  // ---- accumulators + persistent prefetch regs (live across wait_rel) ----
  f32x4 av[12], nx0, nx1;
  bf16x8 pA0[4], pA1[4];   // h fragments (loaded post-barrier in hmain)
  bf16x8 pN0[4], pN1[4];   // n-gate weights: prefetched PRE-barrier (hpre)
  bf16x8 pb0, pb1, pb2, pb3;  // WrzL primer: prefetched PRE-barrier

  __amdgpu_buffer_rsrc_t rnG = mkrsrc(nGp);

  // xpart: ALL waves; w<4 handles rows R..R+15 (a0 slots), w>=4 rows R+16..R+31
  auto xpart = [&](const ushort_t* xp) {
    __amdgpu_buffer_rsrc_t rx = mkrsrc(xp);
    const int R = (w & 3) * 32 + (w >> 2) * 16;
#pragma unroll
    for (int kt = 0; kt < 2; ++kt) {
      bf16x8 a = ldb(rx, ((kt * 4 + fq4) * 128 + R + fr) * 16);
      const ushort_t* bl = WiL + kt * 3072 + l * 8;
      bf16x8 br_0 = *(const bf16x8*)(bl);
      bf16x8 br_1 = *(const bf16x8*)(bl + 512);
      bf16x8 bz_0 = *(const bf16x8*)(bl + 1024);
      bf16x8 bz_1 = *(const bf16x8*)(bl + 1536);
      bf16x8 bn_0 = *(const bf16x8*)(bl + 2048);
      bf16x8 bn_1 = *(const bf16x8*)(bl + 2560);
      if (w < 4) {
        av[0] = MFMA(a, br_0, av[0]);
        av[1] = MFMA(a, br_1, av[1]);
        av[4] = MFMA(a, bz_0, av[4]);
        av[5] = MFMA(a, bz_1, av[5]);
      } else {
        av[2] = MFMA(a, br_0, av[2]);
        av[3] = MFMA(a, br_1, av[3]);
        av[6] = MFMA(a, bz_0, av[6]);
        av[7] = MFMA(a, bz_1, av[7]);
      }
      nx0 = MFMA(a, bn_0, nx0);
      nx1 = MFMA(a, bn_1, nx1);
    }
  };

  // hpre: h-independent prefetch, issued BEFORE the group barrier.
  auto hpre = [&]() {
    const int kh = w >> 2;
#pragma unroll
    for (int i = 0; i < 4; ++i) {
      int kt = kh * 16 + i;
      pN0[i] = ldbc(rnG, kt * 2048 + l * 16);
      pN1[i] = ldbc(rnG, kt * 2048 + 1024 + l * 16);
    }
    const ushort_t* bl0 = WrzL + (kh * 16) * 2048 + l * 8;
    pb0 = *(const bf16x8*)(bl0);
    pb1 = *(const bf16x8*)(bl0 + 512);
    pb2 = *(const bf16x8*)(bl0 + 1024);
    pb3 = *(const bf16x8*)(bl0 + 1536);
  };

  // hmain: A-loads (h-dependent) + the 16-iter MFMA loop.
  auto hmain = [&](const ushort_t* hbp) {
    __amdgpu_buffer_rsrc_t r = mkrsrc(hbp);
    const int kh = w >> 2, R = (w & 3) * 32;
#pragma unroll
    for (int i = 0; i < 4; ++i) {
      int kt = kh * 16 + i;
      pA0[i] = ldb(r, ((kt * 4 + fq4) * 128 + R + fr) * 16);
      pA1[i] = ldb(r, ((kt * 4 + fq4) * 128 + R + 16 + fr) * 16);
    }
    bf16x8 br0 = pb0, br1 = pb1, bz0 = pb2, bz1 = pb3;
#pragma unroll
    for (int i = 0; i < 16; ++i) {
      int kt = kh * 16 + i;
      bf16x8 a0 = pA0[i & 3], a1 = pA1[i & 3];
      bf16x8 n0 = pN0[i & 3], n1 = pN1[i & 3];
      bf16x8 cr0 = br0, cr1 = br1, cz0 = bz0, cz1 = bz1;
      if (i < 15) {  // prefetch next iter's WrzL fragments
        const ushort_t* bln = WrzL + (kt + 1) * 2048 + l * 8;
        br0 = *(const bf16x8*)(bln);
        br1 = *(const bf16x8*)(bln + 512);
        bz0 = *(const bf16x8*)(bln + 1024);
        bz1 = *(const bf16x8*)(bln + 1536);
      }
      if (i < 12) {
        int kp = kt + 4;
        pA0[i & 3] = ldb(r, ((kp * 4 + fq4) * 128 + R + fr) * 16);
        pA1[i & 3] = ldb(r, ((kp * 4 + fq4) * 128 + R + 16 + fr) * 16);
        pN0[i & 3] = ldbc(rnG, kp * 2048 + l * 16);
        pN1[i & 3] = ldbc(rnG, kp * 2048 + 1024 + l * 16);
      }
      av[0] = MFMA(a0, cr0, av[0]);
      av[2] = MFMA(a1, cr0, av[2]);
      av[1] = MFMA(a0, cr1, av[1]);
      av[3] = MFMA(a1, cr1, av[3]);
      av[4] = MFMA(a0, cz0, av[4]);
      av[6] = MFMA(a1, cz0, av[6]);
      av[5] = MFMA(a0, cz1, av[5]);
      av[7] = MFMA(a1, cz1, av[7]);
      av[8] = MFMA(a0, n0, av[8]);
      av[10] = MFMA(a1, n0, av[10]);
      av[9] = MFMA(a0, n1, av[9]);
      av[11] = MFMA(a1, n1, av[11]);
    }
  };

// Symmetric exchange round: w>=4 sends lo-row partials av[LO0],av[LO1]
// (planes 0,1); w<4 sends hi-row partials av[HI0],av[HI1] (planes 2,3).
// TS=0 drops the trailing sync (only valid when arrive's barrier follows
// before any scratch reuse).
#define KXCH(LO0, LO1, HI0, HI1, TS)                                \
  do {                                                              \
    if (w >= 4) {                                                   \
      float* sp_ = scratchF + ((w - 4) * 64 + l) * 4;               \
      *(f32x4*)(sp_) = av[LO0];                                     \
      *(f32x4*)(sp_ + 1024) = av[LO1];                              \
    } else {                                                        \
      float* sp_ = scratchF + (w * 64 + l) * 4;                     \
      *(f32x4*)(sp_ + 2048) = av[HI0];                              \
      *(f32x4*)(sp_ + 3072) = av[HI1];                              \
    }                                                               \
    __syncthreads();                                                \
    if (w < 4) {                                                    \
      const float* sp_ = scratchF + (w * 64 + l) * 4;               \
      av[LO0] += *(const f32x4*)(sp_);                              \
      av[LO1] += *(const f32x4*)(sp_ + 1024);                       \
    } else {                                                        \
      const float* sp_ = scratchF + ((w - 4) * 64 + l) * 4;         \
      av[HI0] += *(const f32x4*)(sp_ + 2048);                       \
      av[HI1] += *(const f32x4*)(sp_ + 3072);                       \
    }                                                               \
    if (TS) __syncthreads();                                        \
  } while (0)

// Epilogue gate-math for one jf; all operands literal-indexed registers.
#define EPI(RV, ZV, NHV, NXV, JF, HC)                                  \
  do {                                                                 \
    const int kq_ = slot * 4 + (JF)*2 + (fr >> 3);                     \
    _Pragma("unroll") for (int v = 0; v < 4; ++v) {                    \
      float rr = sigmf(RV[v] + brz[JF]);                               \
      float zz = sigmf(ZV[v] + bzz[JF]);                               \
      float nn = tanhf_(NXV[v] + bin[JF] + rr * (NHV[v] + bhn[JF]));   \
      float h = (1.f - zz) * nn + zz * HC[v];                          \
      HC[v] = h;                                                       \
      int row_ = Rbase + fq4 * 4 + v;                                  \
      hn[(kq_ * 128 + row_) * 8 + sub_] = f2bf(h);                     \
    }                                                                  \
  } while (0)

  auto fcdo = [&](const ushort_t* hbp, int td, bool wr, ushort_t* innW) {
    __amdgpu_buffer_rsrc_t r = mkrsrc(hbp);
    __amdgpu_buffer_rsrc_t rf = mkrsrc(fcGg);
    const int kh = w >> 2;
    f32x4 fa = (f32x4){0.f, 0.f, 0.f, 0.f};
    bf16x8 Af[4], Bf[4];
#pragma unroll
    for (int i = 0; i < 4; ++i) {
      int kt = kh * 16 + i;
      Af[i] = ldb(r, ((kt * 4 + fq4) * 128 + Rfc + fr) * 16);
      Bf[i] = ldbc(rf, (kt * 4 + jfF) * 1024 + l * 16);
    }
#pragma unroll
    for (int i = 0; i < 16; ++i) {
      int kt = kh * 16 + i;
      bf16x8 a = Af[i & 3], bb = Bf[i & 3];
      if (i < 12) {
        Af[i & 3] = ldb(r, (((kt + 4) * 4 + fq4) * 128 + Rfc + fr) * 16);
        Bf[i & 3] = ldbc(rf, ((kt + 4) * 4 + jfF) * 1024 + l * 16);
      }
      fa = MFMA(a, bb, fa);
    }
    if (w >= 4) *(f32x4*)(scratchF + ((w - 4) * 64 + l) * 4) = fa;
    __syncthreads();
    if (w < 4) {
      fa += *(const f32x4*)(scratchF + (w * 64 + l) * 4);
      const int kq = colF >> 3, sub = colF & 7;
#pragma unroll
      for (int v = 0; v < 4; ++v) {
        int row = Rfc + fq4 * 4 + v;
        float o = fa[v] + inp[v] + fcbF;
        inp[v] = o;
        if (wr) innW[(kq * 128 + row) * 8 + sub] = f2bf(o);
        if (colF < 55) outp[(size_t)(g * 128 + row) * 1375 + td * 55 + colF] = o;
      }
    }
    __syncthreads();  // drains all waves' inn/out stores to L2
  };

  arrive();
  wait_rel(1);

  for (int t = 0; t < 74; ++t) {
#pragma unroll
    for (int i = 0; i < 12; ++i) av[i] = (f32x4){0.f, 0.f, 0.f, 0.f};
    nx0 = (f32x4){0.f, 0.f, 0.f, 0.f};
    nx1 = (f32x4){0.f, 0.f, 0.f, 0.f};

    if (t <= 49) {
      xpart(t <= 48 ? xgg + (size_t)t * 8192 : inng(0));  // all waves, pre-barrier
    }
    if (t > 0) {
      hpre();            // h-independent prefetch fills during the wait
      wait_rel(t + 1);
    }
    if (t >= 50 && isFC) {
      fcdo(hb(t & 1), t - 50, true, inng((t - 49) & 1));
      if (tid == 0) atomicAdd(fcpp(t - 50), 1u);  // fcdo's barrier drained stores
    }
    if (t > 0) hmain(hb(t & 1));
    if (t >= 50) {
      fc_wait(t - 50);
      xpart(inng((t - 49) & 1));  // all waves
    }
    KXCH(0, 1, 2, 3, 1);
    KXCH(4, 5, 6, 7, 1);
    KXCH(8, 9, 10, 11, 0);  // trailing sync dropped: arrive's barrier orders reuse
    {  // epilogue on ALL waves: each wave owns its 16-row half
      ushort_t* hn = hb((t + 1) & 1);
      const int Rbase = (w & 3) * 32 + (w >> 2) * 16;
      const int sub_ = fr & 7;
      if (w < 4) {
        EPI(av[0], av[4], av[8], nx0, 0, hreg0);
        EPI(av[1], av[5], av[9], nx1, 1, hreg1);
      } else {
        EPI(av[2], av[6], av[10], nx0, 0, hreg0);
        EPI(av[3], av[7], av[11], nx1, 1, hreg1);
      }
    }
    arrive();
  }

  if (isFC) {
    wait_rel(75);
    fcdo(hb(0), 24, false, (ushort_t*)0);
  }
}

extern "C" void kernel_launch(void* const* d_in, const int* in_sizes, int n_in,
                              void* d_out, int out_size, void* d_ws, size_t ws_size,
                              hipStream_t stream) {
  const float* enc  = (const float*)d_in[0];
  const float* dec  = (const float*)d_in[1];
  const float* Wih  = (const float*)d_in[2];
  const float* Whh  = (const float*)d_in[3];
  const float* b_ih = (const float*)d_in[4];
  const float* b_hh = (const float*)d_in[5];
  const float* fcw  = (const float*)d_in[6];
  const float* fcb  = (const float*)d_in[7];
  float* out = (float*)d_out;

  char* ws = (char*)d_ws;
  unsigned* cnt  = (unsigned*)ws; ws += 65536;
  ushort_t* xg   = (ushort_t*)ws; ws += (size_t)8 * 49 * 8192 * 2;   // 6.42 MB
  ushort_t* hA   = (ushort_t*)ws; ws += (size_t)8 * 2 * 131072 * 2;  // 4 MB
  ushort_t* innA = (ushort_t*)ws; ws += (size_t)8 * 2 * 8192 * 2;    // 256 KB
  ushort_t* nG   = (ushort_t*)ws; ws += (size_t)8 * 32 * 32768 * 2;  // 16 MB
  ushort_t* fcG  = (ushort_t*)ws; ws += (size_t)8 * 65536 * 2;       // 1 MB

  (void)hipMemsetAsync(cnt, 0, 65536, stream);
  seq2seq_xcd<<<256, 512, 0, stream>>>(
      enc, dec, Wih, Whh, b_ih, b_hh, fcw, fcb, out,
      xg, hA, innA, nG, fcG, cnt);
}

// Round 10
// 752.736 us; speedup vs baseline: 1.9451x; 1.0383x over previous
//
#include <hip/hip_runtime.h>

// Round 16: R15 base (781us champion) + FC GEMM spread across ALL 32 blocks.
// Decoder fcdo was 8 FC blocks running a 16-iter MFMA loop serially before
// hmain (~1.2-1.5us straggle x25 steps, all 32 blocks eat it at the barrier).
// Now: FC output = 8 Mtiles x 4 Ntiles = 32 tiles; block `slot` owns tile
// (slot>>2, slot&3). Its 8 waves K-split 1024 into 8x128 (4 MFMA each), one
// 8-way scratch reduce (8KB, conflict-free), wave 0 adds residual-carry
// inpO + fcb and writes inn/outp. Uniform ~0.3-0.4us on every block, no
// straggler; inn published earlier. Signal: R12-proven tid0-after-trailing-
// sync atomicAdd, fc_wait counts 32. Trailing sync also closes the scratch
// race vs KXCH plane writes. Everything else identical to R15.

typedef unsigned short ushort_t;
typedef __bf16 bf16x8 __attribute__((ext_vector_type(8)));
typedef float f32x4 __attribute__((ext_vector_type(4)));
typedef unsigned int u32x4 __attribute__((ext_vector_type(4)));

#define MFMA(a, b, c) __builtin_amdgcn_mfma_f32_16x16x32_bf16(a, b, c, 0, 0, 0)

static __device__ __forceinline__ ushort_t f2bf(float f) {
  union { float f; unsigned u; } x; x.f = f;
  unsigned r = x.u + 0x7fffu + ((x.u >> 16) & 1u);
  return (ushort_t)(r >> 16);
}
static __device__ __forceinline__ float sigmf(float x) { return 1.f / (1.f + __expf(-x)); }
static __device__ __forceinline__ float tanhf_(float x) { return 1.f - 2.f / (__expf(2.f * x) + 1.f); }

static __device__ __forceinline__ __amdgpu_buffer_rsrc_t mkrsrc(const void* p) {
  return __builtin_amdgcn_make_buffer_rsrc(const_cast<void*>(p), (short)0, -1, 0x00020000);
}
#if __has_builtin(__builtin_amdgcn_raw_buffer_load_b128)
// aux=1 -> sc0: bypass vL1 (h/inn: written by other CUs each step).
static __device__ __forceinline__ bf16x8 ldb(__amdgpu_buffer_rsrc_t r, int voff) {
  u32x4 v = __builtin_amdgcn_raw_buffer_load_b128(r, voff, 0, 1);
  union { u32x4 u; bf16x8 b; } x; x.u = v; return x.b;
}
// aux=0: vL1-cached (weights: immutable, block/group-private).
static __device__ __forceinline__ bf16x8 ldbc(__amdgpu_buffer_rsrc_t r, int voff) {
  u32x4 v = __builtin_amdgcn_raw_buffer_load_b128(r, voff, 0, 0);
  union { u32x4 u; bf16x8 b; } x; x.u = v; return x.b;
}
#else
static __device__ __forceinline__ bf16x8 ldb(__amdgpu_buffer_rsrc_t r, int voff) {
  union { unsigned u[4]; bf16x8 b; } x;
  x.u[0] = __builtin_amdgcn_raw_buffer_load_b32(r, voff, 0, 1);
  x.u[1] = __builtin_amdgcn_raw_buffer_load_b32(r, voff + 4, 0, 1);
  x.u[2] = __builtin_amdgcn_raw_buffer_load_b32(r, voff + 8, 0, 1);
  x.u[3] = __builtin_amdgcn_raw_buffer_load_b32(r, voff + 12, 0, 1);
  return x.b;
}
static __device__ __forceinline__ bf16x8 ldbc(__amdgpu_buffer_rsrc_t r, int voff) {
  union { unsigned u[4]; bf16x8 b; } x;
  x.u[0] = __builtin_amdgcn_raw_buffer_load_b32(r, voff, 0, 0);
  x.u[1] = __builtin_amdgcn_raw_buffer_load_b32(r, voff + 4, 0, 0);
  x.u[2] = __builtin_amdgcn_raw_buffer_load_b32(r, voff + 8, 0, 0);
  x.u[3] = __builtin_amdgcn_raw_buffer_load_b32(r, voff + 12, 0, 0);
  return x.b;
}
#endif

__global__ __launch_bounds__(512, 2)
void seq2seq_xcd(const float* __restrict__ enc, const float* __restrict__ dec,
                 const float* __restrict__ Wih, const float* __restrict__ Whh,
                 const float* __restrict__ b_ih, const float* __restrict__ b_hh,
                 const float* __restrict__ fcw, const float* __restrict__ fcb,
                 float* __restrict__ outp,
                 ushort_t* __restrict__ xg, ushort_t* __restrict__ hA,
                 ushort_t* __restrict__ innA, ushort_t* __restrict__ nG,
                 ushort_t* __restrict__ fcG, unsigned* cnt) {
  __shared__ ushort_t WrzL[65536];  // [kt32][gate2][jf2][512]  128 KB
  __shared__ ushort_t WiL[6144];    // [kt2][gate3][jf2][512]    12 KB
  __shared__ float scratchF[4096];  // 4 planes x 256 slots x f32x4 (conflict-free) 16 KB
  __shared__ unsigned sgs;

  const int tid = threadIdx.x;
  const int w = tid >> 6, l = tid & 63;
  const int fr = l & 15, fq4 = l >> 4;

  // ---- claim XCD-local slot ----
  if (tid == 0) {
    unsigned x;
    asm volatile("s_getreg_b32 %0, hwreg(HW_REG_XCC_ID, 0, 8)" : "=s"(x));
    x &= 7u;
    unsigned s = atomicAdd(&cnt[x * 64], 1u);
    sgs = (x << 8) | s;
  }
  __syncthreads();
  const int g = sgs >> 8, slot = sgs & 255;
  const bool isFC = (slot >= 24);  // init-time fcG staging role only

  // arrive counters: 4 lines per group (lines 8..39); fcpp at 48+.
  unsigned* arr4 = cnt + (8 + g * 4 + (slot & 3)) * 64;
  unsigned* arrb = cnt + (8 + g * 4) * 64;
  auto fcpp = [&](int td) { return cnt + (48 + g * 25 + td) * 64; };

  ushort_t* hbase = hA + (size_t)g * 262144;
  auto hb = [&](int i) { return hbase + (size_t)i * 131072; };
  ushort_t* xgg = xg + (size_t)g * 49 * 8192;
  auto inng = [&](int i) { return innA + (size_t)(g * 2 + i) * 8192; };
  ushort_t* nGp = nG + (size_t)(g * 32 + slot) * 32768;
  ushort_t* fcGg = fcG + (size_t)g * 65536;

  // ---- init conversions (all group-local) ----
  for (int i = tid; i < 65536; i += 512) {  // WrzL
    int j = i & 7, ln = (i >> 3) & 63, jf = (i >> 9) & 1, gt = (i >> 10) & 1, kt = i >> 11;
    int col = gt * 1024 + slot * 32 + jf * 16 + (ln & 15);
    int k = kt * 32 + (ln >> 4) * 8 + j;
    WrzL[i] = f2bf(Whh[(size_t)col * 1024 + k]);
  }
  for (int i = tid; i < 6144; i += 512) {  // WiL (r,z,n)
    int j = i & 7, ln = (i >> 3) & 63, jf = (i >> 9) & 1, rem = i >> 10;
    int gt = rem % 3, kt = rem / 3;
    int col = gt * 1024 + slot * 32 + jf * 16 + (ln & 15);
    int k = kt * 32 + (ln >> 4) * 8 + j;
    WiL[i] = (k < 55) ? f2bf(Wih[(size_t)col * 55 + k]) : (ushort_t)0;
  }
  for (int i = tid; i < 32768; i += 512) {  // nG (block-private)
    int j = i & 7, ln = (i >> 3) & 63, jf = (i >> 9) & 1, kt = i >> 10;
    int col = 2048 + slot * 32 + jf * 16 + (ln & 15);
    int k = kt * 32 + (ln >> 4) * 8 + j;
    nGp[i] = f2bf(Whh[(size_t)col * 1024 + k]);
  }
#pragma unroll
  for (int rep = 0; rep < 2; ++rep) {  // xg: t = slot, slot+32
    int t = slot + rep * 32;
    if (t < 49) {
      ushort_t* xp = xgg + (size_t)t * 8192;
      for (int i = tid; i < 8192; i += 512) {
        int sub = i & 7, row = (i >> 3) & 127, kc = i >> 10;
        int c = kc * 8 + sub;
        xp[i] = (c < 55) ? f2bf(enc[((size_t)(g * 128 + row) * 50 + t) * 55 + c]) : (ushort_t)0;
      }
    }
  }
  if (slot < 4) {  // inn(0) = dec[:,0,:]
    ushort_t* ip = inng(0);
    for (int i = slot * 2048 + tid; i < (slot + 1) * 2048; i += 512) {
      int sub = i & 7, row = (i >> 3) & 127, kc = i >> 10;
      int c = kc * 8 + sub;
      ip[i] = (c < 55) ? f2bf(dec[(size_t)(g * 128 + row) * 1375 + c]) : (ushort_t)0;
    }
  }
  if (isFC) {  // fcG: group-shared, slot s converts kt 4(s-24)..+3
    for (int i = (slot - 24) * 8192 + tid; i < (slot - 23) * 8192; i += 512) {
      int j = i & 7, ln = (i >> 3) & 63, jf = (i >> 9) & 3, kt = i >> 11;
      int c = jf * 16 + (ln & 15);
      int k = kt * 32 + (ln >> 4) * 8 + j;
      fcGg[i] = (c < 55) ? f2bf(fcw[(size_t)c * 1024 + k]) : (ushort_t)0;
    }
  }

  // ---- per-thread constants ----
  float brz[2], bzz[2], bin[2], bhn[2];
#pragma unroll
  for (int jf = 0; jf < 2; ++jf) {
    int col = slot * 32 + jf * 16 + fr;
    brz[jf] = b_ih[col] + b_hh[col];
    bzz[jf] = b_ih[1024 + col] + b_hh[1024 + col];
    bin[jf] = b_ih[2048 + col];
    bhn[jf] = b_hh[2048 + col];
  }
  // FC tile ownership: block owns (Mtile, Ntile) = (slot>>2, slot&3)
  const int Rm = (slot >> 2) * 16;       // FC rows
  const int cn = slot & 3;               // FC col-tile
  const int colO = cn * 16 + fr;         // output col (wave 0 lanes)
  float fcbO = 0.f, inpO[4] = {0.f, 0.f, 0.f, 0.f};
  if (w == 0) {
    fcbO = (colO < 55) ? fcb[colO] : 0.f;
#pragma unroll
    for (int v = 0; v < 4; ++v)
      inpO[v] = (colO < 55) ? dec[(size_t)(g * 128 + Rm + fq4 * 4 + v) * 1375 + colO] : 0.f;
  }
  f32x4 hreg0 = (f32x4){0.f, 0.f, 0.f, 0.f};  // own row-half, jf=0
  f32x4 hreg1 = (f32x4){0.f, 0.f, 0.f, 0.f};  // own row-half, jf=1

  // ---- flat group barrier: 4-line arrive, sum-poll release ----
  auto arrive = [&]() {
    __syncthreads();  // drains vmcnt: all stores complete at (shared) L2
    if (tid == 0) atomicAdd(arr4, 1u);
  };
  auto wait_rel = [&](unsigned k) {
    if (tid == 0) {
      for (;;) {
        unsigned s0 = __hip_atomic_load(arrb, __ATOMIC_RELAXED, __HIP_MEMORY_SCOPE_AGENT);
        unsigned s1 = __hip_atomic_load(arrb + 64, __ATOMIC_RELAXED, __HIP_MEMORY_SCOPE_AGENT);
        unsigned s2 = __hip_atomic_load(arrb + 128, __ATOMIC_RELAXED, __HIP_MEMORY_SCOPE_AGENT);
        unsigned s3 = __hip_atomic_load(arrb + 192, __ATOMIC_RELAXED, __HIP_MEMORY_SCOPE_AGENT);
        if (s0 + s1 + s2 + s3 >= 32u * k) break;
        __builtin_amdgcn_s_sleep(1);
      }
    }
    __syncthreads();
  };
  auto fc_wait = [&](int td) {  // 32 blocks publish their FC tiles
    if (tid == 0) {
      while (__hip_atomic_load(fcpp(td), __ATOMIC_RELAXED, __HIP_MEMORY_SCOPE_AGENT) < 32u)
        __builtin_amdgcn_s_sleep(1);
    }
    __syncthreads();
  };

  // ---- accumulators + persistent prefetch regs (live across wait_rel) ----
  f32x4 av[12], nx0, nx1;
  bf16x8 pA0[4], pA1[4];   // h fragments (loaded post-barrier in hmain)
  bf16x8 pN0[4], pN1[4];   // n-gate weights: prefetched PRE-barrier (hpre)
  bf16x8 pb0, pb1, pb2, pb3;  // WrzL primer: prefetched PRE-barrier

  __amdgpu_buffer_rsrc_t rnG = mkrsrc(nGp);

  // xpart: ALL waves; w<4 handles rows R..R+15 (a0 slots), w>=4 rows R+16..R+31
  auto xpart = [&](const ushort_t* xp) {
    __amdgpu_buffer_rsrc_t rx = mkrsrc(xp);
    const int R = (w & 3) * 32 + (w >> 2) * 16;
#pragma unroll
    for (int kt = 0; kt < 2; ++kt) {
      bf16x8 a = ldb(rx, ((kt * 4 + fq4) * 128 + R + fr) * 16);
      const ushort_t* bl = WiL + kt * 3072 + l * 8;
      bf16x8 br_0 = *(const bf16x8*)(bl);
      bf16x8 br_1 = *(const bf16x8*)(bl + 512);
      bf16x8 bz_0 = *(const bf16x8*)(bl + 1024);
      bf16x8 bz_1 = *(const bf16x8*)(bl + 1536);
      bf16x8 bn_0 = *(const bf16x8*)(bl + 2048);
      bf16x8 bn_1 = *(const bf16x8*)(bl + 2560);
      if (w < 4) {
        av[0] = MFMA(a, br_0, av[0]);
        av[1] = MFMA(a, br_1, av[1]);
        av[4] = MFMA(a, bz_0, av[4]);
        av[5] = MFMA(a, bz_1, av[5]);
      } else {
        av[2] = MFMA(a, br_0, av[2]);
        av[3] = MFMA(a, br_1, av[3]);
        av[6] = MFMA(a, bz_0, av[6]);
        av[7] = MFMA(a, bz_1, av[7]);
      }
      nx0 = MFMA(a, bn_0, nx0);
      nx1 = MFMA(a, bn_1, nx1);
    }
  };

  // hpre: h-independent prefetch, issued BEFORE the group barrier.
  auto hpre = [&]() {
    const int kh = w >> 2;
#pragma unroll
    for (int i = 0; i < 4; ++i) {
      int kt = kh * 16 + i;
      pN0[i] = ldbc(rnG, kt * 2048 + l * 16);
      pN1[i] = ldbc(rnG, kt * 2048 + 1024 + l * 16);
    }
    const ushort_t* bl0 = WrzL + (kh * 16) * 2048 + l * 8;
    pb0 = *(const bf16x8*)(bl0);
    pb1 = *(const bf16x8*)(bl0 + 512);
    pb2 = *(const bf16x8*)(bl0 + 1024);
    pb3 = *(const bf16x8*)(bl0 + 1536);
  };

  // hmain: A-loads (h-dependent) + the 16-iter MFMA loop.
  auto hmain = [&](const ushort_t* hbp) {
    __amdgpu_buffer_rsrc_t r = mkrsrc(hbp);
    const int kh = w >> 2, R = (w & 3) * 32;
#pragma unroll
    for (int i = 0; i < 4; ++i) {
      int kt = kh * 16 + i;
      pA0[i] = ldb(r, ((kt * 4 + fq4) * 128 + R + fr) * 16);
      pA1[i] = ldb(r, ((kt * 4 + fq4) * 128 + R + 16 + fr) * 16);
    }
    bf16x8 br0 = pb0, br1 = pb1, bz0 = pb2, bz1 = pb3;
#pragma unroll
    for (int i = 0; i < 16; ++i) {
      int kt = kh * 16 + i;
      bf16x8 a0 = pA0[i & 3], a1 = pA1[i & 3];
      bf16x8 n0 = pN0[i & 3], n1 = pN1[i & 3];
      bf16x8 cr0 = br0, cr1 = br1, cz0 = bz0, cz1 = bz1;
      if (i < 15) {  // prefetch next iter's WrzL fragments
        const ushort_t* bln = WrzL + (kt + 1) * 2048 + l * 8;
        br0 = *(const bf16x8*)(bln);
        br1 = *(const bf16x8*)(bln + 512);
        bz0 = *(const bf16x8*)(bln + 1024);
        bz1 = *(const bf16x8*)(bln + 1536);
      }
      if (i < 12) {
        int kp = kt + 4;
        pA0[i & 3] = ldb(r, ((kp * 4 + fq4) * 128 + R + fr) * 16);
        pA1[i & 3] = ldb(r, ((kp * 4 + fq4) * 128 + R + 16 + fr) * 16);
        pN0[i & 3] = ldbc(rnG, kp * 2048 + l * 16);
        pN1[i & 3] = ldbc(rnG, kp * 2048 + 1024 + l * 16);
      }
      av[0] = MFMA(a0, cr0, av[0]);
      av[2] = MFMA(a1, cr0, av[2]);
      av[1] = MFMA(a0, cr1, av[1]);
      av[3] = MFMA(a1, cr1, av[3]);
      av[4] = MFMA(a0, cz0, av[4]);
      av[6] = MFMA(a1, cz0, av[6]);
      av[5] = MFMA(a0, cz1, av[5]);
      av[7] = MFMA(a1, cz1, av[7]);
      av[8] = MFMA(a0, n0, av[8]);
      av[10] = MFMA(a1, n0, av[10]);
      av[9] = MFMA(a0, n1, av[9]);
      av[11] = MFMA(a1, n1, av[11]);
    }
  };

// Symmetric exchange round: w>=4 sends lo-row partials av[LO0],av[LO1]
// (planes 0,1); w<4 sends hi-row partials av[HI0],av[HI1] (planes 2,3).
// TS=0 drops the trailing sync (only valid when arrive's barrier follows
// before any scratch reuse).
#define KXCH(LO0, LO1, HI0, HI1, TS)                                \
  do {                                                              \
    if (w >= 4) {                                                   \
      float* sp_ = scratchF + ((w - 4) * 64 + l) * 4;               \
      *(f32x4*)(sp_) = av[LO0];                                     \
      *(f32x4*)(sp_ + 1024) = av[LO1];                              \
    } else {                                                        \
      float* sp_ = scratchF + (w * 64 + l) * 4;                     \
      *(f32x4*)(sp_ + 2048) = av[HI0];                              \
      *(f32x4*)(sp_ + 3072) = av[HI1];                              \
    }                                                               \
    __syncthreads();                                                \
    if (w < 4) {                                                    \
      const float* sp_ = scratchF + (w * 64 + l) * 4;               \
      av[LO0] += *(const f32x4*)(sp_);                              \
      av[LO1] += *(const f32x4*)(sp_ + 1024);                       \
    } else {                                                        \
      const float* sp_ = scratchF + ((w - 4) * 64 + l) * 4;         \
      av[HI0] += *(const f32x4*)(sp_ + 2048);                       \
      av[HI1] += *(const f32x4*)(sp_ + 3072);                       \
    }                                                               \
    if (TS) __syncthreads();                                        \
  } while (0)

// Epilogue gate-math for one jf; all operands literal-indexed registers.
#define EPI(RV, ZV, NHV, NXV, JF, HC)                                  \
  do {                                                                 \
    const int kq_ = slot * 4 + (JF)*2 + (fr >> 3);                     \
    _Pragma("unroll") for (int v = 0; v < 4; ++v) {                    \
      float rr = sigmf(RV[v] + brz[JF]);                               \
      float zz = sigmf(ZV[v] + bzz[JF]);                               \
      float nn = tanhf_(NXV[v] + bin[JF] + rr * (NHV[v] + bhn[JF]));   \
      float h = (1.f - zz) * nn + zz * HC[v];                          \
      HC[v] = h;                                                       \
      int row_ = Rbase + fq4 * 4 + v;                                  \
      hn[(kq_ * 128 + row_) * 8 + sub_] = f2bf(h);                     \
    }                                                                  \
  } while (0)

  // FC tile GEMM on ALL 32 blocks: 8 waves K-split 1024 -> 4 MFMA each,
  // 8-way scratch reduce (8KB, 16B/lane conflict-free), wave 0 finishes.
  auto fcdo32 = [&](const ushort_t* hbp, int td, bool wr, ushort_t* innW) {
    __amdgpu_buffer_rsrc_t r = mkrsrc(hbp);
    __amdgpu_buffer_rsrc_t rf = mkrsrc(fcGg);
    bf16x8 Af[4], Bf[4];
#pragma unroll
    for (int i = 0; i < 4; ++i) {
      int kt = w * 4 + i;
      Af[i] = ldb(r, ((kt * 4 + fq4) * 128 + Rm + fr) * 16);
      Bf[i] = ldbc(rf, (kt * 4 + cn) * 1024 + l * 16);
    }
    f32x4 fa = (f32x4){0.f, 0.f, 0.f, 0.f};
#pragma unroll
    for (int i = 0; i < 4; ++i) fa = MFMA(Af[i], Bf[i], fa);
    *(f32x4*)(scratchF + (w * 64 + l) * 4) = fa;
    __syncthreads();
    if (w == 0) {
      f32x4 s = *(const f32x4*)(scratchF + l * 4);
#pragma unroll
      for (int ww = 1; ww < 8; ++ww)
        s += *(const f32x4*)(scratchF + (ww * 64 + l) * 4);
      const int kq = colO >> 3, sub = colO & 7;
#pragma unroll
      for (int v = 0; v < 4; ++v) {
        int row = Rm + fq4 * 4 + v;
        float o = s[v] + inpO[v] + fcbO;
        inpO[v] = o;  // residual carry (block owns this tile every step)
        if (wr) innW[(kq * 128 + row) * 8 + sub] = f2bf(o);
        if (colO < 55) outp[(size_t)(g * 128 + row) * 1375 + td * 55 + colO] = o;
      }
    }
    __syncthreads();  // drains wave0 stores for signal; guards scratch vs KXCH
  };

  arrive();
  wait_rel(1);

  for (int t = 0; t < 74; ++t) {
#pragma unroll
    for (int i = 0; i < 12; ++i) av[i] = (f32x4){0.f, 0.f, 0.f, 0.f};
    nx0 = (f32x4){0.f, 0.f, 0.f, 0.f};
    nx1 = (f32x4){0.f, 0.f, 0.f, 0.f};

    if (t <= 49) {
      xpart(t <= 48 ? xgg + (size_t)t * 8192 : inng(0));  // all waves, pre-barrier
    }
    if (t > 0) {
      hpre();            // h-independent prefetch fills during the wait
      wait_rel(t + 1);
    }
    if (t >= 50) {
      fcdo32(hb(t & 1), t - 50, true, inng((t - 49) & 1));
      if (tid == 0) atomicAdd(fcpp(t - 50), 1u);  // fcdo32's barrier drained stores
    }
    if (t > 0) hmain(hb(t & 1));
    if (t >= 50) {
      fc_wait(t - 50);
      xpart(inng((t - 49) & 1));  // all waves
    }
    KXCH(0, 1, 2, 3, 1);
    KXCH(4, 5, 6, 7, 1);
    KXCH(8, 9, 10, 11, 0);  // trailing sync dropped: arrive's barrier orders reuse
    {  // epilogue on ALL waves: each wave owns its 16-row half
      ushort_t* hn = hb((t + 1) & 1);
      const int Rbase = (w & 3) * 32 + (w >> 2) * 16;
      const int sub_ = fr & 7;
      if (w < 4) {
        EPI(av[0], av[4], av[8], nx0, 0, hreg0);
        EPI(av[1], av[5], av[9], nx1, 1, hreg1);
      } else {
        EPI(av[2], av[6], av[10], nx0, 0, hreg0);
        EPI(av[3], av[7], av[11], nx1, 1, hreg1);
      }
    }
    arrive();
  }

  wait_rel(75);
  fcdo32(hb(0), 24, false, (ushort_t*)0);
}

extern "C" void kernel_launch(void* const* d_in, const int* in_sizes, int n_in,
                              void* d_out, int out_size, void* d_ws, size_t ws_size,
                              hipStream_t stream) {
  const float* enc  = (const float*)d_in[0];
  const float* dec  = (const float*)d_in[1];
  const float* Wih  = (const float*)d_in[2];
  const float* Whh  = (const float*)d_in[3];
  const float* b_ih = (const float*)d_in[4];
  const float* b_hh = (const float*)d_in[5];
  const float* fcw  = (const float*)d_in[6];
  const float* fcb  = (const float*)d_in[7];
  float* out = (float*)d_out;

  char* ws = (char*)d_ws;
  unsigned* cnt  = (unsigned*)ws; ws += 65536;
  ushort_t* xg   = (ushort_t*)ws; ws += (size_t)8 * 49 * 8192 * 2;   // 6.42 MB
  ushort_t* hA   = (ushort_t*)ws; ws += (size_t)8 * 2 * 131072 * 2;  // 4 MB
  ushort_t* innA = (ushort_t*)ws; ws += (size_t)8 * 2 * 8192 * 2;    // 256 KB
  ushort_t* nG   = (ushort_t*)ws; ws += (size_t)8 * 32 * 32768 * 2;  // 16 MB
  ushort_t* fcG  = (ushort_t*)ws; ws += (size_t)8 * 65536 * 2;       // 1 MB

  (void)hipMemsetAsync(cnt, 0, 65536, stream);
  seq2seq_xcd<<<256, 512, 0, stream>>>(
      enc, dec, Wih, Whh, b_ih, b_hh, fcw, fcb, out,
      xg, hA, innA, nG, fcG, cnt);
}